// Round 1
// baseline (7356.863 us; speedup 1.0000x reference)
//
#include <hip/hip_runtime.h>
#include <stdint.h>

// ---------------------------------------------------------------------------
// Threefry-2x32, 20 rounds — bit-exact match of jax._src.prng.threefry2x32
// ---------------------------------------------------------------------------
static __device__ __forceinline__ uint32_t rotl32(uint32_t v, int n) {
  return (v << n) | (v >> (32 - n));
}

static __device__ __forceinline__ void threefry2x32(
    uint32_t k0, uint32_t k1, uint32_t x0, uint32_t x1,
    uint32_t& o0, uint32_t& o1)
{
  const uint32_t ks2 = k0 ^ k1 ^ 0x1BD11BDAu;
  x0 += k0; x1 += k1;

  x0 += x1; x1 = rotl32(x1, 13); x1 ^= x0;
  x0 += x1; x1 = rotl32(x1, 15); x1 ^= x0;
  x0 += x1; x1 = rotl32(x1, 26); x1 ^= x0;
  x0 += x1; x1 = rotl32(x1,  6); x1 ^= x0;
  x0 += k1; x1 += ks2 + 1u;

  x0 += x1; x1 = rotl32(x1, 17); x1 ^= x0;
  x0 += x1; x1 = rotl32(x1, 29); x1 ^= x0;
  x0 += x1; x1 = rotl32(x1, 16); x1 ^= x0;
  x0 += x1; x1 = rotl32(x1, 24); x1 ^= x0;
  x0 += ks2; x1 += k0 + 2u;

  x0 += x1; x1 = rotl32(x1, 13); x1 ^= x0;
  x0 += x1; x1 = rotl32(x1, 15); x1 ^= x0;
  x0 += x1; x1 = rotl32(x1, 26); x1 ^= x0;
  x0 += x1; x1 = rotl32(x1,  6); x1 ^= x0;
  x0 += k0; x1 += k1 + 3u;

  x0 += x1; x1 = rotl32(x1, 17); x1 ^= x0;
  x0 += x1; x1 = rotl32(x1, 29); x1 ^= x0;
  x0 += x1; x1 = rotl32(x1, 16); x1 ^= x0;
  x0 += x1; x1 = rotl32(x1, 24); x1 ^= x0;
  x0 += k1; x1 += ks2 + 4u;

  x0 += x1; x1 = rotl32(x1, 13); x1 ^= x0;
  x0 += x1; x1 = rotl32(x1, 15); x1 ^= x0;
  x0 += x1; x1 = rotl32(x1, 26); x1 ^= x0;
  x0 += x1; x1 = rotl32(x1,  6); x1 ^= x0;
  x0 += ks2; x1 += k0 + 5u;

  o0 = x0; o1 = x1;
}

// ---------------------------------------------------------------------------
// erfinv, single precision — same Giles polynomial as XLA's ErfInv32
// ---------------------------------------------------------------------------
static __device__ __forceinline__ float erfinv_f(float x) {
  float t = fmaf(x, -x, 1.0f);   // 1 - x^2 (fma: slightly MORE accurate than ref)
  float w = -__logf(t);
  float p;
  if (w < 5.0f) {
    w = w - 2.5f;
    p =              2.81022636e-08f;
    p = fmaf(p, w,   3.43273939e-07f);
    p = fmaf(p, w,  -3.5233877e-06f);
    p = fmaf(p, w,  -4.39150654e-06f);
    p = fmaf(p, w,   0.00021858087f);
    p = fmaf(p, w,  -0.00125372503f);
    p = fmaf(p, w,  -0.00417768164f);
    p = fmaf(p, w,   0.246640727f);
    p = fmaf(p, w,   1.50140941f);
  } else {
    w = sqrtf(w) - 3.0f;
    p =             -0.000200214257f;
    p = fmaf(p, w,   0.000100950558f);
    p = fmaf(p, w,   0.00134934322f);
    p = fmaf(p, w,  -0.00367342844f);
    p = fmaf(p, w,   0.00573950773f);
    p = fmaf(p, w,  -0.0076224613f);
    p = fmaf(p, w,   0.00943887047f);
    p = fmaf(p, w,   1.00167406f);
    p = fmaf(p, w,   2.83297682f);
  }
  return p * x;
}

#define NSAMP 400
#define NC 512

// One wave (64 lanes) per row; 8 columns per lane. 4 waves / block.
__global__ __launch_bounds__(256) void mc_softmax_kernel(
    const float* __restrict__ mean, const float* __restrict__ var,
    float* __restrict__ out)
{
  // Per-block precompute of the 400 sample keys (fold-like split):
  //   key_s = threefry2x32((0, 42), (0, s))
  __shared__ uint32_t kb0[NSAMP];
  __shared__ uint32_t kb1[NSAMP];
  for (int s = threadIdx.x; s < NSAMP; s += 256) {
    uint32_t a, b;
    threefry2x32(0u, 42u, 0u, (uint32_t)s, a, b);
    kb0[s] = a; kb1[s] = b;
  }
  __syncthreads();

  const int lane  = threadIdx.x & 63;
  const int row   = (blockIdx.x << 2) + (threadIdx.x >> 6);
  const int cbase = lane << 2;   // columns cbase..cbase+3 and 256+cbase..

  const float* mr = mean + (size_t)row * NC;
  const float* vr = var  + (size_t)row * NC;

  float m[8], sd[8], acc[8], e[8];
  {
    float4 t0 = *(const float4*)(mr + cbase);
    float4 t1 = *(const float4*)(mr + 256 + cbase);
    m[0] = t0.x; m[1] = t0.y; m[2] = t0.z; m[3] = t0.w;
    m[4] = t1.x; m[5] = t1.y; m[6] = t1.z; m[7] = t1.w;
    float4 v0 = *(const float4*)(vr + cbase);
    float4 v1 = *(const float4*)(vr + 256 + cbase);
    sd[0] = sqrtf(v0.x); sd[1] = sqrtf(v0.y); sd[2] = sqrtf(v0.z); sd[3] = sqrtf(v0.w);
    sd[4] = sqrtf(v1.x); sd[5] = sqrtf(v1.y); sd[6] = sqrtf(v1.z); sd[7] = sqrtf(v1.w);
  }
#pragma unroll
  for (int j = 0; j < 8; ++j) acc[j] = 0.0f;

  const uint32_t base = (uint32_t)(row * NC + cbase);
  const float lo = -0.99999994f;          // nextafter(-1, 0) in f32
  const float sqrt2 = 1.41421356237f;     // rounds to 0x3FB504F3, == f32(sqrt(2))

  for (int s = 0; s < NSAMP; ++s) {
    const uint32_t k0 = kb0[s];
    const uint32_t k1 = kb1[s];
    float sum = 0.0f;
#pragma unroll
    for (int j = 0; j < 8; ++j) {
      // flat index of (row, c); partitionable counter = (hi=0, lo=flat)
      const uint32_t cnt = base + (uint32_t)(j < 4 ? j : 252 + j);
      uint32_t y0, y1;
      threefry2x32(k0, k1, 0u, cnt, y0, y1);
      const uint32_t bits = y0 ^ y1;      // partitionable 32-bit fold
      // uniform in [lo, 1):  f in [0,1);  (maxval-minval) rounds to 2.0f
      float f = __uint_as_float((bits >> 9) | 0x3f800000u) - 1.0f;
      float u = fmaxf(lo, fmaf(f, 2.0f, lo));
      float nrm = sqrt2 * erfinv_f(u);
      float lg  = fmaf(nrm, sd[j], m[j]); // mean + eps*std  (|lg| <~ 11, exp safe)
      float ex  = __expf(lg);
      e[j] = ex;
      sum += ex;
    }
    // wave-wide denominator (no max-subtract needed; mathematically identical)
#pragma unroll
    for (int off = 32; off >= 1; off >>= 1)
      sum += __shfl_xor(sum, off);
    const float inv = __builtin_amdgcn_rcpf(sum);
#pragma unroll
    for (int j = 0; j < 8; ++j)
      acc[j] = fmaf(e[j], inv, acc[j]);
  }

  float* orow = out + (size_t)row * NC;
  const float sc = 1.0f / (float)NSAMP;
  float4 o0, o1;
  o0.x = acc[0] * sc; o0.y = acc[1] * sc; o0.z = acc[2] * sc; o0.w = acc[3] * sc;
  o1.x = acc[4] * sc; o1.y = acc[5] * sc; o1.z = acc[6] * sc; o1.w = acc[7] * sc;
  *(float4*)(orow + cbase)       = o0;
  *(float4*)(orow + 256 + cbase) = o1;
}

extern "C" void kernel_launch(void* const* d_in, const int* in_sizes, int n_in,
                              void* d_out, int out_size, void* d_ws, size_t ws_size,
                              hipStream_t stream) {
  const float* mean = (const float*)d_in[0];
  const float* var  = (const float*)d_in[1];
  float* out        = (float*)d_out;

  const int rows = out_size / NC;        // 16384
  const int blocks = rows / 4;           // 4 rows (waves) per 256-thread block
  mc_softmax_kernel<<<blocks, 256, 0, stream>>>(mean, var, out);
}

// Round 2
// 7100.887 us; speedup vs baseline: 1.0360x; 1.0360x over previous
//
#include <hip/hip_runtime.h>
#include <stdint.h>

// ---------------------------------------------------------------------------
// Threefry-2x32, 20 rounds — bit-exact match of jax._src.prng.threefry2x32
// ---------------------------------------------------------------------------
static __device__ __forceinline__ uint32_t rotl32(uint32_t v, int n) {
  return (v << n) | (v >> (32 - n));   // compiles to v_alignbit_b32 (1 op)
}

static __device__ __forceinline__ void threefry2x32(
    uint32_t k0, uint32_t k1, uint32_t x0, uint32_t x1,
    uint32_t& o0, uint32_t& o1)
{
  const uint32_t ks2 = k0 ^ k1 ^ 0x1BD11BDAu;
  x0 += k0; x1 += k1;

  x0 += x1; x1 = rotl32(x1, 13); x1 ^= x0;
  x0 += x1; x1 = rotl32(x1, 15); x1 ^= x0;
  x0 += x1; x1 = rotl32(x1, 26); x1 ^= x0;
  x0 += x1; x1 = rotl32(x1,  6); x1 ^= x0;
  x0 += k1; x1 += ks2 + 1u;

  x0 += x1; x1 = rotl32(x1, 17); x1 ^= x0;
  x0 += x1; x1 = rotl32(x1, 29); x1 ^= x0;
  x0 += x1; x1 = rotl32(x1, 16); x1 ^= x0;
  x0 += x1; x1 = rotl32(x1, 24); x1 ^= x0;
  x0 += ks2; x1 += k0 + 2u;

  x0 += x1; x1 = rotl32(x1, 13); x1 ^= x0;
  x0 += x1; x1 = rotl32(x1, 15); x1 ^= x0;
  x0 += x1; x1 = rotl32(x1, 26); x1 ^= x0;
  x0 += x1; x1 = rotl32(x1,  6); x1 ^= x0;
  x0 += k0; x1 += k1 + 3u;

  x0 += x1; x1 = rotl32(x1, 17); x1 ^= x0;
  x0 += x1; x1 = rotl32(x1, 29); x1 ^= x0;
  x0 += x1; x1 = rotl32(x1, 16); x1 ^= x0;
  x0 += x1; x1 = rotl32(x1, 24); x1 ^= x0;
  x0 += k1; x1 += ks2 + 4u;

  x0 += x1; x1 = rotl32(x1, 13); x1 ^= x0;
  x0 += x1; x1 = rotl32(x1, 15); x1 ^= x0;
  x0 += x1; x1 = rotl32(x1, 26); x1 ^= x0;
  x0 += x1; x1 = rotl32(x1,  6); x1 ^= x0;
  x0 += ks2; x1 += k0 + 5u;

  o0 = x0; o1 = x1;
}

// ---------------------------------------------------------------------------
// erfinv, single precision — same Giles polynomial as XLA's ErfInv32.
// Tail branch (|u| > 0.99665, ~0.3%/lane) uses fast v_sqrt_f32: sub-ulp-level
// difference vs correctly-rounded sqrt, ~46x slack under the 2.85e-3 threshold.
// ---------------------------------------------------------------------------
static __device__ __forceinline__ float erfinv_f(float x) {
  float t = fmaf(x, -x, 1.0f);
  float w = -__logf(t);
  float p;
  if (w < 5.0f) {
    w = w - 2.5f;
    p =              2.81022636e-08f;
    p = fmaf(p, w,   3.43273939e-07f);
    p = fmaf(p, w,  -3.5233877e-06f);
    p = fmaf(p, w,  -4.39150654e-06f);
    p = fmaf(p, w,   0.00021858087f);
    p = fmaf(p, w,  -0.00125372503f);
    p = fmaf(p, w,  -0.00417768164f);
    p = fmaf(p, w,   0.246640727f);
    p = fmaf(p, w,   1.50140941f);
  } else {
    w = __builtin_amdgcn_sqrtf(w) - 3.0f;
    p =             -0.000200214257f;
    p = fmaf(p, w,   0.000100950558f);
    p = fmaf(p, w,   0.00134934322f);
    p = fmaf(p, w,  -0.00367342844f);
    p = fmaf(p, w,   0.00573950773f);
    p = fmaf(p, w,  -0.0076224613f);
    p = fmaf(p, w,   0.00943887047f);
    p = fmaf(p, w,   1.00167406f);
    p = fmaf(p, w,   2.83297682f);
  }
  return p * x;
}

#define NSAMP 400
#define NC 512

// One wave (64 lanes) per row; 8 columns per lane. 4 waves / block.
// __launch_bounds__(256, 4): 4 waves/EU min -> 128-VGPR budget. R1's default
// squeezed the kernel to 36 VGPRs, forcing the ~32 live floats/lane into
// spills/AGPR traffic and serializing the 8 dependent threefry chains.
__global__ __launch_bounds__(256, 4) void mc_softmax_kernel(
    const float* __restrict__ mean, const float* __restrict__ var,
    float* __restrict__ out)
{
  // Per-block precompute of the 400 sample keys: key_s = threefry((0,42),(0,s))
  __shared__ uint2 kb[NSAMP];
  for (int s = threadIdx.x; s < NSAMP; s += 256) {
    uint32_t a, b;
    threefry2x32(0u, 42u, 0u, (uint32_t)s, a, b);
    kb[s] = make_uint2(a, b);
  }
  __syncthreads();

  const int lane  = threadIdx.x & 63;
  const int row   = (blockIdx.x << 2) + (threadIdx.x >> 6);
  const int cbase = lane << 2;   // columns cbase..cbase+3 and 256+cbase..

  const float* mr = mean + (size_t)row * NC;
  const float* vr = var  + (size_t)row * NC;

  float m[8], sd[8], acc[8], e[8];
  {
    float4 t0 = *(const float4*)(mr + cbase);
    float4 t1 = *(const float4*)(mr + 256 + cbase);
    m[0] = t0.x; m[1] = t0.y; m[2] = t0.z; m[3] = t0.w;
    m[4] = t1.x; m[5] = t1.y; m[6] = t1.z; m[7] = t1.w;
    float4 v0 = *(const float4*)(vr + cbase);
    float4 v1 = *(const float4*)(vr + 256 + cbase);
    sd[0] = sqrtf(v0.x); sd[1] = sqrtf(v0.y); sd[2] = sqrtf(v0.z); sd[3] = sqrtf(v0.w);
    sd[4] = sqrtf(v1.x); sd[5] = sqrtf(v1.y); sd[6] = sqrtf(v1.z); sd[7] = sqrtf(v1.w);
  }
#pragma unroll
  for (int j = 0; j < 8; ++j) acc[j] = 0.0f;

  const uint32_t base = (uint32_t)(row * NC + cbase);
  const float lo = -0.99999994f;          // nextafter(-1, 0) in f32
  const float sqrt2 = 1.41421356237f;

  for (int s = 0; s < NSAMP; ++s) {
    const uint2 kk = kb[s];
    const uint32_t k0 = kk.x;
    const uint32_t k1 = kk.y;
    float sum = 0.0f;
#pragma unroll
    for (int j = 0; j < 8; ++j) {
      // flat index of (row, c); partitionable counter = (hi=0, lo=flat)
      const uint32_t cnt = base + (uint32_t)(j < 4 ? j : 252 + j);
      uint32_t y0, y1;
      threefry2x32(k0, k1, 0u, cnt, y0, y1);
      const uint32_t bits = y0 ^ y1;      // partitionable 32-bit fold
      // uniform in [lo, 1): f in [0,1); fma(f,2,lo) >= lo always (lo is
      // representable, exact value >= lo, RN preserves) — JAX's max() is identity.
      float f = __uint_as_float((bits >> 9) | 0x3f800000u) - 1.0f;
      float u = fmaf(f, 2.0f, lo);
      float nrm = sqrt2 * erfinv_f(u);
      float lg  = fmaf(nrm, sd[j], m[j]); // |lg| <~ 11, exp safe without max-sub
      float ex  = __expf(lg);
      e[j] = ex;
      sum += ex;
    }
    // wave-wide denominator
#pragma unroll
    for (int off = 32; off >= 1; off >>= 1)
      sum += __shfl_xor(sum, off);
    const float inv = __builtin_amdgcn_rcpf(sum);
#pragma unroll
    for (int j = 0; j < 8; ++j)
      acc[j] = fmaf(e[j], inv, acc[j]);
  }

  float* orow = out + (size_t)row * NC;
  const float sc = 1.0f / (float)NSAMP;
  float4 o0, o1;
  o0.x = acc[0] * sc; o0.y = acc[1] * sc; o0.z = acc[2] * sc; o0.w = acc[3] * sc;
  o1.x = acc[4] * sc; o1.y = acc[5] * sc; o1.z = acc[6] * sc; o1.w = acc[7] * sc;
  *(float4*)(orow + cbase)       = o0;
  *(float4*)(orow + 256 + cbase) = o1;
}

extern "C" void kernel_launch(void* const* d_in, const int* in_sizes, int n_in,
                              void* d_out, int out_size, void* d_ws, size_t ws_size,
                              hipStream_t stream) {
  const float* mean = (const float*)d_in[0];
  const float* var  = (const float*)d_in[1];
  float* out        = (float*)d_out;

  const int rows = out_size / NC;        // 16384
  const int blocks = rows / 4;           // 4 rows (waves) per 256-thread block
  mc_softmax_kernel<<<blocks, 256, 0, stream>>>(mean, var, out);
}